// Round 5
// baseline (439.563 us; speedup 1.0000x reference)
//
#include <hip/hip_runtime.h>
#include <math.h>

// ---------------------------------------------------------------------------
// QuantumAutoEncoder. Round 5: circuit gate coefficients broadcast from a
// per-lane VGPR table via v_readlane (lane g holds gate g's 8 coeffs) --
// eliminates the per-gate scalar-load latency chain that left VALUBusy at 28%.
// Rest identical to Round 4 (split-K=2 batch GEMMs, W12 fusion, bf16x3 MFMA).
// ---------------------------------------------------------------------------

#define B_SZ 4096
#define EMB 1024
#define NQ 10
#define NL 3

typedef __bf16 bf16x8 __attribute__((ext_vector_type(8)));
typedef float f32x4 __attribute__((ext_vector_type(4)));
typedef unsigned short u16x8 __attribute__((ext_vector_type(8)));

__device__ __forceinline__ unsigned short f2bf_rne(float f) {
    unsigned int u = __float_as_uint(f);
    u += 0x7FFFu + ((u >> 16) & 1u);
    return (unsigned short)(u >> 16);
}
__device__ __forceinline__ float bf2f(unsigned short h) {
    return __uint_as_float(((unsigned int)h) << 16);
}
__device__ __forceinline__ float lane_bcast(float v, int l) {
    return __uint_as_float(__builtin_amdgcn_readlane(__float_as_uint(v), l));
}

__device__ __forceinline__ void gll16(const void* g, void* l) {
    __builtin_amdgcn_global_load_lds(
        (const __attribute__((address_space(1))) void*)g,
        (__attribute__((address_space(3))) void*)l, 16, 0, 0);
}

// --------------------------- MFMA GEMM (bf16x3) ----------------------------
#define GBM 128
#define GBN 128
#define GBK 32

__global__ __launch_bounds__(512) void gemm3_mfma(
    const unsigned short* __restrict__ Ah, const unsigned short* __restrict__ Al,
    const unsigned short* __restrict__ Bh, const unsigned short* __restrict__ Bl,
    const float* __restrict__ bias, float* __restrict__ C,
    int Kp, int Np, int Ksplit, size_t zStride)
{
    __shared__ __align__(16) char lds[32768];
    char* ldsAh = lds;
    char* ldsAl = lds + 8192;
    char* ldsBh = lds + 16384;
    char* ldsBl = lds + 24576;

    const int tid = threadIdx.x;
    const int lane = tid & 63;
    const int wv = tid >> 6;
    const int wm = wv >> 1;
    const int wn = wv & 1;
    const int blockRow = blockIdx.y * GBM;
    const int blockCol = blockIdx.x * GBN;
    const int z = blockIdx.z;

    const int srow = tid >> 2;
    const int skel = (tid & 3) * 8;
    const size_t aOff = ((size_t)(blockRow + srow) * Kp + skel + (size_t)z * Ksplit) * 2;
    const size_t bOff = ((size_t)(blockCol + srow) * Kp + skel + (size_t)z * Ksplit) * 2;
    const char* aHp = (const char*)Ah + aOff;
    const char* aLp = (const char*)Al + aOff;
    const char* bHp = (const char*)Bh + bOff;
    const char* bLp = (const char*)Bl + bOff;
    const int stageOff = wv * 1024;

    f32x4 acc[2][4];
    #pragma unroll
    for (int i = 0; i < 2; ++i)
        #pragma unroll
        for (int j = 0; j < 4; ++j)
            #pragma unroll
            for (int r = 0; r < 4; ++r) acc[i][j][r] = 0.f;

    const int kq = (lane >> 4) * 16;
    int aFragOff[2], bFragOff[4];
    #pragma unroll
    for (int i = 0; i < 2; ++i) aFragOff[i] = (wm * 32 + i * 16 + (lane & 15)) * 64 + kq;
    #pragma unroll
    for (int j = 0; j < 4; ++j) bFragOff[j] = (wn * 64 + j * 16 + (lane & 15)) * 64 + kq;

    const int nsteps = Ksplit / GBK;
    for (int s = 0; s < nsteps; ++s) {
        const size_t kb = (size_t)s * GBK * 2;
        gll16(aHp + kb, ldsAh + stageOff);
        gll16(aLp + kb, ldsAl + stageOff);
        gll16(bHp + kb, ldsBh + stageOff);
        gll16(bLp + kb, ldsBl + stageOff);
        __syncthreads();

        bf16x8 ah[2], al[2], bh[4], bl[4];
        #pragma unroll
        for (int i = 0; i < 2; ++i) {
            ah[i] = *(const bf16x8*)(ldsAh + aFragOff[i]);
            al[i] = *(const bf16x8*)(ldsAl + aFragOff[i]);
        }
        #pragma unroll
        for (int j = 0; j < 4; ++j) {
            bh[j] = *(const bf16x8*)(ldsBh + bFragOff[j]);
            bl[j] = *(const bf16x8*)(ldsBl + bFragOff[j]);
        }
        #pragma unroll
        for (int j = 0; j < 4; ++j)
            #pragma unroll
            for (int i = 0; i < 2; ++i) {
                acc[i][j] = __builtin_amdgcn_mfma_f32_16x16x32_bf16(al[i], bh[j], acc[i][j], 0, 0, 0);
                acc[i][j] = __builtin_amdgcn_mfma_f32_16x16x32_bf16(ah[i], bl[j], acc[i][j], 0, 0, 0);
                acc[i][j] = __builtin_amdgcn_mfma_f32_16x16x32_bf16(ah[i], bh[j], acc[i][j], 0, 0, 0);
            }
        __syncthreads();
    }

    float* Cz = C + (size_t)z * zStride;
    const bool addB = (z == 0) && (bias != nullptr);
    const int rquad = (lane >> 4) * 4;
    const int cidx = lane & 15;
    #pragma unroll
    for (int i = 0; i < 2; ++i)
        #pragma unroll
        for (int j = 0; j < 4; ++j) {
            #pragma unroll
            for (int r = 0; r < 4; ++r) {
                int row = blockRow + wm * 32 + i * 16 + rquad + r;
                int col = blockCol + wn * 64 + j * 16 + cidx;
                float v = acc[i][j][r];
                if (addB) v += bias[col];
                Cz[(size_t)row * Np + col] = v;
            }
        }
}

// ------------------- weight transpose + split + pad ------------------------
__global__ __launch_bounds__(256) void tsplit_kernel(
    const float* __restrict__ W, unsigned short* __restrict__ H, unsigned short* __restrict__ L,
    int K, int N, int Kp)
{
    __shared__ float tile[32][33];
    const int tid = threadIdx.x;
    const int tx = tid & 31, ty = tid >> 5;
    const int k0 = blockIdx.x * 32, n0 = blockIdx.y * 32;
    #pragma unroll
    for (int i = 0; i < 4; ++i) {
        int k = k0 + ty + i * 8, n = n0 + tx;
        tile[ty + i * 8][tx] = (k < K && n < N) ? W[(size_t)k * N + n] : 0.f;
    }
    __syncthreads();
    #pragma unroll
    for (int i = 0; i < 4; ++i) {
        int n = n0 + ty + i * 8, k = k0 + tx;
        float v = tile[tx][ty + i * 8];
        size_t o = (size_t)n * Kp + k;
        unsigned short h = f2bf_rne(v);
        H[o] = h;
        L[o] = f2bf_rne(v - bf2f(h));
    }
}

// tsplit over the sum of 4 split-K partials: P = 4 x [1024][1024] fp32.
__global__ __launch_bounds__(256) void tsplit4_kernel(
    const float* __restrict__ P, unsigned short* __restrict__ H, unsigned short* __restrict__ L)
{
    __shared__ float tile[32][33];
    const int tid = threadIdx.x;
    const int tx = tid & 31, ty = tid >> 5;
    const int k0 = blockIdx.x * 32, n0 = blockIdx.y * 32;
    #pragma unroll
    for (int i = 0; i < 4; ++i) {
        int k = k0 + ty + i * 8, n = n0 + tx;
        size_t o = (size_t)k * 1024 + n;
        tile[ty + i * 8][tx] = P[o] + P[o + (1u << 20)] + P[o + (2u << 20)] + P[o + (3u << 20)];
    }
    __syncthreads();
    #pragma unroll
    for (int i = 0; i < 4; ++i) {
        int n = n0 + ty + i * 8, k = k0 + tx;
        float v = tile[tx][ty + i * 8];
        size_t o = (size_t)n * 1024 + k;
        unsigned short h = f2bf_rne(v);
        H[o] = h;
        L[o] = f2bf_rne(v - bf2f(h));
    }
}

// -------------------- activation split + pad (rows) ------------------------
__global__ __launch_bounds__(256) void split_rows_kernel(
    const float* __restrict__ X, unsigned short* __restrict__ H, unsigned short* __restrict__ L,
    int C, int Cp)
{
    const int r = blockIdx.x;
    for (int c = threadIdx.x; c < Cp; c += 256) {
        float v = (c < C) ? X[(size_t)r * C + c] : 0.f;
        unsigned short h = f2bf_rne(v);
        size_t o = (size_t)r * Cp + c;
        H[o] = h;
        L[o] = f2bf_rne(v - bf2f(h));
    }
}

__global__ void padbias_kernel(const float* __restrict__ b, float* __restrict__ bp, int N, int Np) {
    int i = blockIdx.x * 256 + threadIdx.x;
    if (i < Np) bp[i] = (i < N) ? b[i] : 0.f;
}

// b12[n] = sum_j b1[j] * W2[j,n] + b2[n].
__global__ __launch_bounds__(256) void b12_kernel(
    const float* __restrict__ b1, const float* __restrict__ W2,
    const float* __restrict__ b2, float* __restrict__ b12)
{
    __shared__ float red[4][64];
    const int tx = threadIdx.x & 63;
    const int ty = threadIdx.x >> 6;
    const int n = blockIdx.x * 64 + tx;
    float s = 0.f;
    for (int j = ty * 512; j < (ty + 1) * 512; ++j)
        s += b1[j] * W2[(size_t)j * 1024 + n];
    red[ty][tx] = s;
    __syncthreads();
    if (ty == 0) b12[n] = red[0][tx] + red[1][tx] + red[2][tx] + red[3][tx] + b2[n];
}

// ----------------------- gate matrix precompute ----------------------------
// Layout for readlane broadcast: enc gate g -> G[g*8..], dec gate g -> G[512+g*8..].
// Lanes 30..63 of each half are unused (may hold poison; never consumed).
__global__ void gatecoef_kernel(const float* __restrict__ wEnc,
                                const float* __restrict__ wDec,
                                float* __restrict__ G)
{
    int g = threadIdx.x;
    if (g >= 60) return;
    const float* w = (g < 30) ? (wEnc + g * 3) : (wDec + (g - 30) * 3);
    float* o = G + ((g < 30) ? g : (g - 30 + 64)) * 8;
    float phi = w[0], th = w[1], om = w[2];
    float ch = cosf(0.5f * th), sh = sinf(0.5f * th);
    float ap = 0.5f * (phi + om), am = 0.5f * (phi - om);
    float cap = cosf(ap), sap = sinf(ap);
    float cam = cosf(am), sam = sinf(am);
    o[0] =  cap * ch; o[1] = -sap * ch;
    o[2] = -cam * sh; o[3] = -sam * sh;
    o[4] =  cam * sh; o[5] = -sam * sh;
    o[6] =  cap * ch; o[7] =  sap * ch;
}

// ----------------- register-resident quantum circuit -----------------------
// amp idx = (lane<<4)|reg. Wire q stride S=1<<(9-q); S<16 reg bit, else lane bit.
// Gate coefficients: lane GATE of tbl[0..7] holds {are,aim,bre,bim,cre,cim,dre,dim}.

template<int GATE, int Q>
__device__ __forceinline__ void apply_rot(float (&xr)[16], float (&xi)[16],
                                          const float (&tbl)[8], int lane)
{
    float are = lane_bcast(tbl[0], GATE), aim = lane_bcast(tbl[1], GATE);
    float bre = lane_bcast(tbl[2], GATE), bim = lane_bcast(tbl[3], GATE);
    float cre = lane_bcast(tbl[4], GATE), cim = lane_bcast(tbl[5], GATE);
    float dre = lane_bcast(tbl[6], GATE), dim_ = lane_bcast(tbl[7], GATE);
    constexpr int S = 1 << (9 - Q);
    if constexpr (S < 16) {
        #pragma unroll
        for (int p = 0; p < 8; ++p) {
            int r0 = (p / S) * (2 * S) + (p % S);
            int r1 = r0 + S;
            float x0r = xr[r0], x0i = xi[r0], x1r = xr[r1], x1i = xi[r1];
            xr[r0] = are * x0r - aim * x0i + bre * x1r - bim * x1i;
            xi[r0] = are * x0i + aim * x0r + bre * x1i + bim * x1r;
            xr[r1] = cre * x0r - cim * x0i + dre * x1r - dim_ * x1i;
            xi[r1] = cre * x0i + cim * x0r + dre * x1i + dim_ * x1r;
        }
    } else {
        constexpr int M = S >> 4;
        bool bit = (lane & M) != 0;
        float pre = bit ? dre : are, pim = bit ? dim_ : aim;
        float qre = bit ? cre : bre, qim = bit ? cim : bim;
        #pragma unroll
        for (int r = 0; r < 16; ++r) {
            float ore = __shfl_xor(xr[r], M, 64);
            float oim = __shfl_xor(xi[r], M, 64);
            float nr = pre * xr[r] - pim * xi[r] + qre * ore - qim * oim;
            float ni = pre * xi[r] + pim * xr[r] + qre * oim + qim * ore;
            xr[r] = nr; xi[r] = ni;
        }
    }
}

template<int C, int T>
__device__ __forceinline__ void apply_cnot(float (&xr)[16], float (&xi)[16], int lane)
{
    constexpr int SC = 1 << (9 - C), ST = 1 << (9 - T);
    if constexpr (SC < 16 && ST < 16) {
        #pragma unroll
        for (int r = 0; r < 16; ++r) {
            if ((r & SC) && !(r & ST)) {
                int j = r | ST;
                float t;
                t = xr[r]; xr[r] = xr[j]; xr[j] = t;
                t = xi[r]; xi[r] = xi[j]; xi[j] = t;
            }
        }
    } else if constexpr (SC < 16) {
        constexpr int MT = ST >> 4;
        #pragma unroll
        for (int r = 0; r < 16; ++r) {
            if (r & SC) {
                xr[r] = __shfl_xor(xr[r], MT, 64);
                xi[r] = __shfl_xor(xi[r], MT, 64);
            }
        }
    } else if constexpr (ST < 16) {
        constexpr int MC = SC >> 4;
        bool bit = (lane & MC) != 0;
        #pragma unroll
        for (int r = 0; r < 16; ++r) {
            if (!(r & ST)) {
                int j = r | ST;
                float a0 = xr[r], a1 = xr[j];
                xr[r] = bit ? a1 : a0;  xr[j] = bit ? a0 : a1;
                float b0 = xi[r], b1 = xi[j];
                xi[r] = bit ? b1 : b0;  xi[j] = bit ? b0 : b1;
            }
        }
    } else {
        constexpr int MC = SC >> 4, MT = ST >> 4;
        bool bit = (lane & MC) != 0;
        #pragma unroll
        for (int r = 0; r < 16; ++r) {
            float o = __shfl_xor(xr[r], MT, 64);
            xr[r] = bit ? o : xr[r];
            float oi = __shfl_xor(xi[r], MT, 64);
            xi[r] = bit ? oi : xi[r];
        }
    }
}

template<int L, int Q>
__device__ __forceinline__ void rots(float (&xr)[16], float (&xi)[16],
                                     const float (&tbl)[8], int lane) {
    apply_rot<L * 10 + Q, Q>(xr, xi, tbl, lane);
    if constexpr (Q < 9) rots<L, Q + 1>(xr, xi, tbl, lane);
}
template<int L, int Q>
__device__ __forceinline__ void cnots(float (&xr)[16], float (&xi)[16], int lane) {
    constexpr int R = (L % 9) + 1;
    apply_cnot<Q, (Q + R) % 10>(xr, xi, lane);
    if constexpr (Q < 9) cnots<L, Q + 1>(xr, xi, lane);
}

// X = X0 + X1 (split-K partials) -> circuit -> hi/lo bf16 split probs.
__global__ __launch_bounds__(256, 4) void circuit_reg_kernel(
    const float* __restrict__ X0, const float* __restrict__ X1,
    unsigned short* __restrict__ Ph, unsigned short* __restrict__ Pl,
    const float* __restrict__ G)
{
    const int lane = threadIdx.x & 63;
    const int item = blockIdx.x * 4 + (threadIdx.x >> 6);
    const size_t base = (size_t)item * 1024 + lane * 16;

    // per-lane coefficient table: lane g holds gate g's 8 coeffs
    float tbl[8];
    {
        const float4* gp = (const float4*)(G + lane * 8);
        float4 t0 = gp[0], t1 = gp[1];
        tbl[0] = t0.x; tbl[1] = t0.y; tbl[2] = t0.z; tbl[3] = t0.w;
        tbl[4] = t1.x; tbl[5] = t1.y; tbl[6] = t1.z; tbl[7] = t1.w;
    }

    float xr[16], xi[16];
    const float4* xb0 = (const float4*)(X0 + base);
    const float4* xb1 = (const float4*)(X1 + base);
    #pragma unroll
    for (int v = 0; v < 4; ++v) {
        float4 f = xb0[v], g = xb1[v];
        xr[v * 4 + 0] = f.x + g.x; xr[v * 4 + 1] = f.y + g.y;
        xr[v * 4 + 2] = f.z + g.z; xr[v * 4 + 3] = f.w + g.w;
    }
    #pragma unroll
    for (int r = 0; r < 16; ++r) xi[r] = 0.f;

    float nrm = 0.f;
    #pragma unroll
    for (int r = 0; r < 16; ++r) nrm += xr[r] * xr[r];
    #pragma unroll
    for (int m = 32; m >= 1; m >>= 1) nrm += __shfl_xor(nrm, m, 64);
    float inv = 1.0f / sqrtf(nrm);
    #pragma unroll
    for (int r = 0; r < 16; ++r) xr[r] *= inv;

    rots<0, 0>(xr, xi, tbl, lane);  cnots<0, 0>(xr, xi, lane);
    rots<1, 0>(xr, xi, tbl, lane);  cnots<1, 0>(xr, xi, lane);
    rots<2, 0>(xr, xi, tbl, lane);  cnots<2, 0>(xr, xi, lane);

    u16x8 h[2], lo[2];
    #pragma unroll
    for (int r = 0; r < 16; ++r) {
        float p = xr[r] * xr[r] + xi[r] * xi[r];
        unsigned short hh = f2bf_rne(p);
        h[r >> 3][r & 7] = hh;
        lo[r >> 3][r & 7] = f2bf_rne(p - bf2f(hh));
    }
    *(u16x8*)(Ph + base) = h[0];
    *(u16x8*)(Ph + base + 8) = h[1];
    *(u16x8*)(Pl + base) = lo[0];
    *(u16x8*)(Pl + base + 8) = lo[1];
}

// ------------------------- abs + row-normalize -----------------------------
__global__ __launch_bounds__(256) void absnorm_kernel(
    const float* __restrict__ X0, const float* __restrict__ X1,
    float* __restrict__ out, int N, int stride)
{
    __shared__ float red[4];
    const int row = blockIdx.x;
    const int tid = threadIdx.x;
    const float* x0 = X0 + (size_t)row * stride;
    const float* x1 = X1 + (size_t)row * stride;

    float s = 0.f;
    for (int i = tid; i < N; i += 256) s += fabsf(x0[i] + x1[i]);
    #pragma unroll
    for (int off = 32; off > 0; off >>= 1) s += __shfl_down(s, off);
    if ((tid & 63) == 0) red[tid >> 6] = s;
    __syncthreads();
    float inv = 1.0f / (red[0] + red[1] + red[2] + red[3]);
    for (int i = tid; i < N; i += 256)
        out[(size_t)row * N + i] = fabsf(x0[i] + x1[i]) * inv;
}

// ---------------------------------------------------------------------------
extern "C" void kernel_launch(void* const* d_in, const int* in_sizes, int n_in,
                              void* d_out, int out_size, void* d_ws, size_t ws_size,
                              hipStream_t stream)
{
    const float* inputs = (const float*)d_in[0];
    const float* wEnc   = (const float*)d_in[1];
    const float* wDec   = (const float*)d_in[2];
    const float* W0     = (const float*)d_in[3];
    const float* b0     = (const float*)d_in[4];
    const float* W1     = (const float*)d_in[5];
    const float* b1     = (const float*)d_in[6];
    const float* W2     = (const float*)d_in[7];
    const float* b2     = (const float*)d_in[8];
    const float* W3     = (const float*)d_in[9];
    const float* b3     = (const float*)d_in[10];
    float* out = (float*)d_out;

    char* w = (char*)d_ws;
    auto alloc = [&](size_t bytes) { char* p = w; w += (bytes + 255) & ~(size_t)255; return p; };

    unsigned short* Bt0h  = (unsigned short*)alloc((size_t)1024 * 1024 * 2);
    unsigned short* Bt0l  = (unsigned short*)alloc((size_t)1024 * 1024 * 2);
    unsigned short* Bt2h  = (unsigned short*)alloc((size_t)1024 * 2048 * 2);
    unsigned short* Bt2l  = (unsigned short*)alloc((size_t)1024 * 2048 * 2);
    unsigned short* Bt3h  = (unsigned short*)alloc((size_t)1024 * 1024 * 2);
    unsigned short* Bt3l  = (unsigned short*)alloc((size_t)1024 * 1024 * 2);
    unsigned short* Bt12h = (unsigned short*)alloc((size_t)1024 * 1024 * 2);
    unsigned short* Bt12l = (unsigned short*)alloc((size_t)1024 * 1024 * 2);
    unsigned short* W1h   = (unsigned short*)alloc((size_t)1024 * 2048 * 2);
    unsigned short* W1l   = (unsigned short*)alloc((size_t)1024 * 2048 * 2);
    float*          b3p   = (float*)alloc(1024 * 4);
    float*          b12   = (float*)alloc(1024 * 4);
    float*          G     = (float*)alloc(2 * 512 * 4);   // enc @ G, dec @ G+512
    unsigned short* Ah    = (unsigned short*)alloc((size_t)B_SZ * 1024 * 2);
    unsigned short* Al    = (unsigned short*)alloc((size_t)B_SZ * 1024 * 2);
    unsigned short* ph    = (unsigned short*)alloc((size_t)B_SZ * 1024 * 2);
    unsigned short* pl    = (unsigned short*)alloc((size_t)B_SZ * 1024 * 2);
    float*          P     = (float*)alloc((size_t)2 * B_SZ * 1024 * 4);  // split-K partials
    float* P12 = P;                 // 4 x [1024x1024] fp32 aliased; dead before G0
    const size_t ZS = (size_t)B_SZ * 1024;

    dim3 blk256(256);

    // ---- per-call prep ----
    tsplit_kernel<<<dim3(32, 32), blk256, 0, stream>>>(W0, Bt0h, Bt0l, 1000, 1024, 1024);
    tsplit_kernel<<<dim3(64, 32), blk256, 0, stream>>>(W2, Bt2h, Bt2l, 2048, 1024, 2048);
    tsplit_kernel<<<dim3(32, 32), blk256, 0, stream>>>(W3, Bt3h, Bt3l, 1024, 1000, 1024);
    split_rows_kernel<<<1024, blk256, 0, stream>>>(W1, W1h, W1l, 2048, 2048);
    padbias_kernel<<<4, blk256, 0, stream>>>(b3, b3p, 1000, 1024);
    b12_kernel<<<16, blk256, 0, stream>>>(b1, W2, b2, b12);
    gatecoef_kernel<<<1, 64, 0, stream>>>(wEnc, wDec, G);
    split_rows_kernel<<<B_SZ, blk256, 0, stream>>>(inputs, Ah, Al, 1000, 1024);

    // ---- W12 = W1 @ W2 (split-K=4) -> transpose+split -> Bt12 ----
    gemm3_mfma<<<dim3(8, 8, 4), 512, 0, stream>>>(
        W1h, W1l, Bt2h, Bt2l, nullptr, P12, 2048, 1024, 512, (size_t)1 << 20);
    tsplit4_kernel<<<dim3(32, 32), blk256, 0, stream>>>(P12, Bt12h, Bt12l);

    // ---- pipeline ----
    gemm3_mfma<<<dim3(8, 32, 2), 512, 0, stream>>>(
        Ah, Al, Bt0h, Bt0l, b0, P, 1024, 1024, 512, ZS);
    circuit_reg_kernel<<<B_SZ / 4, blk256, 0, stream>>>(P, P + ZS, ph, pl, G);
    gemm3_mfma<<<dim3(8, 32, 2), 512, 0, stream>>>(
        ph, pl, Bt12h, Bt12l, b12, P, 1024, 1024, 512, ZS);
    circuit_reg_kernel<<<B_SZ / 4, blk256, 0, stream>>>(P, P + ZS, ph, pl, G + 512);
    gemm3_mfma<<<dim3(8, 32, 2), 512, 0, stream>>>(
        ph, pl, Bt3h, Bt3l, b3p, P, 1024, 1024, 512, ZS);
    absnorm_kernel<<<B_SZ, blk256, 0, stream>>>(P, P + ZS, out, 1000, 1024);
}

// Round 6
// 413.397 us; speedup vs baseline: 1.0633x; 1.0633x over previous
//
#include <hip/hip_runtime.h>
#include <math.h>

// ---------------------------------------------------------------------------
// QuantumAutoEncoder. Round 6: circuit cross-lane ops specialized per mask --
// xor1/2 -> DPP quad_perm, xor8 -> DPP row_ror:8 (VALU pipe, no DS unit),
// xor4/16 -> ds_swizzle immediate (no addr calc), xor32 -> shfl. Halves DS
// traffic and removes shfl address-calc VALU. Also: prep kernels merged
// (8 launches -> 2), W12 GEMM split-K=8. Rest as round 5.
// ---------------------------------------------------------------------------

#define B_SZ 4096
#define EMB 1024
#define NQ 10
#define NL 3

typedef __bf16 bf16x8 __attribute__((ext_vector_type(8)));
typedef float f32x4 __attribute__((ext_vector_type(4)));
typedef unsigned short u16x8 __attribute__((ext_vector_type(8)));

__device__ __forceinline__ unsigned short f2bf_rne(float f) {
    unsigned int u = __float_as_uint(f);
    u += 0x7FFFu + ((u >> 16) & 1u);
    return (unsigned short)(u >> 16);
}
__device__ __forceinline__ float bf2f(unsigned short h) {
    return __uint_as_float(((unsigned int)h) << 16);
}
__device__ __forceinline__ float lane_bcast(float v, int l) {
    return __uint_as_float(__builtin_amdgcn_readlane(__float_as_uint(v), l));
}

// cross-lane xor-M exchange, cheapest primitive per mask:
//  M=1: quad_perm [1,0,3,2]=0xB1   M=2: quad_perm [2,3,0,1]=0x4E   (DPP, VALU)
//  M=8: row_ror:8 = 0x128  ((i+8)%16 == i^8)                       (DPP, VALU)
//  M=4: ds_swizzle 0x101F  M=16: ds_swizzle 0x401F  (BitMode xor)  (DS, no addr)
//  M=32: __shfl_xor (crosses 32-lane swizzle boundary)
template<int M>
__device__ __forceinline__ float lane_xor(float v) {
    if constexpr (M == 1)
        return __uint_as_float(__builtin_amdgcn_mov_dpp(__float_as_uint(v), 0xB1, 0xF, 0xF, true));
    else if constexpr (M == 2)
        return __uint_as_float(__builtin_amdgcn_mov_dpp(__float_as_uint(v), 0x4E, 0xF, 0xF, true));
    else if constexpr (M == 8)
        return __uint_as_float(__builtin_amdgcn_mov_dpp(__float_as_uint(v), 0x128, 0xF, 0xF, true));
    else if constexpr (M == 4)
        return __uint_as_float(__builtin_amdgcn_ds_swizzle(__float_as_uint(v), 0x101F));
    else if constexpr (M == 16)
        return __uint_as_float(__builtin_amdgcn_ds_swizzle(__float_as_uint(v), 0x401F));
    else
        return __shfl_xor(v, 32, 64);
}

__device__ __forceinline__ void gll16(const void* g, void* l) {
    __builtin_amdgcn_global_load_lds(
        (const __attribute__((address_space(1))) void*)g,
        (__attribute__((address_space(3))) void*)l, 16, 0, 0);
}

// --------------------------- MFMA GEMM (bf16x3) ----------------------------
#define GBM 128
#define GBN 128
#define GBK 32

__global__ __launch_bounds__(512) void gemm3_mfma(
    const unsigned short* __restrict__ Ah, const unsigned short* __restrict__ Al,
    const unsigned short* __restrict__ Bh, const unsigned short* __restrict__ Bl,
    const float* __restrict__ bias, float* __restrict__ C,
    int Kp, int Np, int Ksplit, size_t zStride)
{
    __shared__ __align__(16) char lds[32768];
    char* ldsAh = lds;
    char* ldsAl = lds + 8192;
    char* ldsBh = lds + 16384;
    char* ldsBl = lds + 24576;

    const int tid = threadIdx.x;
    const int lane = tid & 63;
    const int wv = tid >> 6;
    const int wm = wv >> 1;
    const int wn = wv & 1;
    const int blockRow = blockIdx.y * GBM;
    const int blockCol = blockIdx.x * GBN;
    const int z = blockIdx.z;

    const int srow = tid >> 2;
    const int skel = (tid & 3) * 8;
    const size_t aOff = ((size_t)(blockRow + srow) * Kp + skel + (size_t)z * Ksplit) * 2;
    const size_t bOff = ((size_t)(blockCol + srow) * Kp + skel + (size_t)z * Ksplit) * 2;
    const char* aHp = (const char*)Ah + aOff;
    const char* aLp = (const char*)Al + aOff;
    const char* bHp = (const char*)Bh + bOff;
    const char* bLp = (const char*)Bl + bOff;
    const int stageOff = wv * 1024;

    f32x4 acc[2][4];
    #pragma unroll
    for (int i = 0; i < 2; ++i)
        #pragma unroll
        for (int j = 0; j < 4; ++j)
            #pragma unroll
            for (int r = 0; r < 4; ++r) acc[i][j][r] = 0.f;

    const int kq = (lane >> 4) * 16;
    int aFragOff[2], bFragOff[4];
    #pragma unroll
    for (int i = 0; i < 2; ++i) aFragOff[i] = (wm * 32 + i * 16 + (lane & 15)) * 64 + kq;
    #pragma unroll
    for (int j = 0; j < 4; ++j) bFragOff[j] = (wn * 64 + j * 16 + (lane & 15)) * 64 + kq;

    const int nsteps = Ksplit / GBK;
    for (int s = 0; s < nsteps; ++s) {
        const size_t kb = (size_t)s * GBK * 2;
        gll16(aHp + kb, ldsAh + stageOff);
        gll16(aLp + kb, ldsAl + stageOff);
        gll16(bHp + kb, ldsBh + stageOff);
        gll16(bLp + kb, ldsBl + stageOff);
        __syncthreads();

        bf16x8 ah[2], al[2], bh[4], bl[4];
        #pragma unroll
        for (int i = 0; i < 2; ++i) {
            ah[i] = *(const bf16x8*)(ldsAh + aFragOff[i]);
            al[i] = *(const bf16x8*)(ldsAl + aFragOff[i]);
        }
        #pragma unroll
        for (int j = 0; j < 4; ++j) {
            bh[j] = *(const bf16x8*)(ldsBh + bFragOff[j]);
            bl[j] = *(const bf16x8*)(ldsBl + bFragOff[j]);
        }
        #pragma unroll
        for (int j = 0; j < 4; ++j)
            #pragma unroll
            for (int i = 0; i < 2; ++i) {
                acc[i][j] = __builtin_amdgcn_mfma_f32_16x16x32_bf16(al[i], bh[j], acc[i][j], 0, 0, 0);
                acc[i][j] = __builtin_amdgcn_mfma_f32_16x16x32_bf16(ah[i], bl[j], acc[i][j], 0, 0, 0);
                acc[i][j] = __builtin_amdgcn_mfma_f32_16x16x32_bf16(ah[i], bh[j], acc[i][j], 0, 0, 0);
            }
        __syncthreads();
    }

    float* Cz = C + (size_t)z * zStride;
    const bool addB = (z == 0) && (bias != nullptr);
    const int rquad = (lane >> 4) * 4;
    const int cidx = lane & 15;
    #pragma unroll
    for (int i = 0; i < 2; ++i)
        #pragma unroll
        for (int j = 0; j < 4; ++j) {
            #pragma unroll
            for (int r = 0; r < 4; ++r) {
                int row = blockRow + wm * 32 + i * 16 + rquad + r;
                int col = blockCol + wn * 64 + j * 16 + cidx;
                float v = acc[i][j][r];
                if (addB) v += bias[col];
                Cz[(size_t)row * Np + col] = v;
            }
        }
}

// ------------------- weight prep (merged single dispatch) ------------------
__device__ __forceinline__ void tsplit_block(
    const float* __restrict__ W, unsigned short* __restrict__ H, unsigned short* __restrict__ L,
    int K, int N, int Kp, int bx, int by, int tid)
{
    __shared__ float tile[32][33];
    const int tx = tid & 31, ty = tid >> 5;
    const int k0 = bx * 32, n0 = by * 32;
    #pragma unroll
    for (int i = 0; i < 4; ++i) {
        int k = k0 + ty + i * 8, n = n0 + tx;
        tile[ty + i * 8][tx] = (k < K && n < N) ? W[(size_t)k * N + n] : 0.f;
    }
    __syncthreads();
    #pragma unroll
    for (int i = 0; i < 4; ++i) {
        int n = n0 + ty + i * 8, k = k0 + tx;
        float v = tile[tx][ty + i * 8];
        size_t o = (size_t)n * Kp + k;
        unsigned short h = f2bf_rne(v);
        H[o] = h;
        L[o] = f2bf_rne(v - bf2f(h));
    }
}

// grid 5120: [0,1024) W0-tsplit, [1024,3072) W2-tsplit, [3072,4096) W3-tsplit,
// [4096,5120) W1 row-split (no transpose).
__global__ __launch_bounds__(256) void prep_weights_kernel(
    const float* __restrict__ W0, unsigned short* __restrict__ Bt0h, unsigned short* __restrict__ Bt0l,
    const float* __restrict__ W2, unsigned short* __restrict__ Bt2h, unsigned short* __restrict__ Bt2l,
    const float* __restrict__ W3, unsigned short* __restrict__ Bt3h, unsigned short* __restrict__ Bt3l,
    const float* __restrict__ W1, unsigned short* __restrict__ W1h, unsigned short* __restrict__ W1l)
{
    const int bid = blockIdx.x;
    const int tid = threadIdx.x;
    if (bid < 1024) {
        tsplit_block(W0, Bt0h, Bt0l, 1000, 1024, 1024, bid & 31, bid >> 5, tid);
    } else if (bid < 3072) {
        int b = bid - 1024;
        tsplit_block(W2, Bt2h, Bt2l, 2048, 1024, 2048, b & 63, b >> 6, tid);
    } else if (bid < 4096) {
        int b = bid - 3072;
        tsplit_block(W3, Bt3h, Bt3l, 1024, 1000, 1024, b & 31, b >> 5, tid);
    } else {
        int r = bid - 4096;
        for (int c = tid; c < 2048; c += 256) {
            float v = W1[(size_t)r * 2048 + c];
            unsigned short h = f2bf_rne(v);
            size_t o = (size_t)r * 2048 + c;
            W1h[o] = h;
            W1l[o] = f2bf_rne(v - bf2f(h));
        }
    }
}

// grid 21: [0,16) b12, [16,20) padbias b3, 20 gatecoef.
__global__ __launch_bounds__(256) void prep_misc_kernel(
    const float* __restrict__ b1, const float* __restrict__ W2, const float* __restrict__ b2,
    float* __restrict__ b12,
    const float* __restrict__ b3, float* __restrict__ b3p,
    const float* __restrict__ wEnc, const float* __restrict__ wDec, float* __restrict__ G)
{
    __shared__ float red[4][64];
    const int bid = blockIdx.x;
    const int tid = threadIdx.x;
    if (bid < 16) {
        const int tx = tid & 63, ty = tid >> 6;
        const int n = bid * 64 + tx;
        float s = 0.f;
        for (int j = ty * 512; j < (ty + 1) * 512; ++j)
            s += b1[j] * W2[(size_t)j * 1024 + n];
        red[ty][tx] = s;
        __syncthreads();
        if (ty == 0) b12[n] = red[0][tx] + red[1][tx] + red[2][tx] + red[3][tx] + b2[n];
    } else if (bid < 20) {
        int i = (bid - 16) * 256 + tid;
        b3p[i] = (i < 1000) ? b3[i] : 0.f;
    } else {
        int g = tid;
        if (g < 60) {
            const float* w = (g < 30) ? (wEnc + g * 3) : (wDec + (g - 30) * 3);
            float* o = G + ((g < 30) ? g : (g - 30 + 64)) * 8;
            float phi = w[0], th = w[1], om = w[2];
            float ch = cosf(0.5f * th), sh = sinf(0.5f * th);
            float ap = 0.5f * (phi + om), am = 0.5f * (phi - om);
            float cap = cosf(ap), sap = sinf(ap);
            float cam = cosf(am), sam = sinf(am);
            o[0] =  cap * ch; o[1] = -sap * ch;
            o[2] = -cam * sh; o[3] = -sam * sh;
            o[4] =  cam * sh; o[5] = -sam * sh;
            o[6] =  cap * ch; o[7] =  sap * ch;
        }
    }
}

// tsplit over the sum of 8 split-K partials: P = 8 x [1024][1024] fp32.
__global__ __launch_bounds__(256) void tsplit8_kernel(
    const float* __restrict__ P, unsigned short* __restrict__ H, unsigned short* __restrict__ L)
{
    __shared__ float tile[32][33];
    const int tid = threadIdx.x;
    const int tx = tid & 31, ty = tid >> 5;
    const int k0 = blockIdx.x * 32, n0 = blockIdx.y * 32;
    #pragma unroll
    for (int i = 0; i < 4; ++i) {
        int k = k0 + ty + i * 8, n = n0 + tx;
        size_t o = (size_t)k * 1024 + n;
        float s = 0.f;
        #pragma unroll
        for (int zz = 0; zz < 8; ++zz) s += P[o + ((size_t)zz << 20)];
        tile[ty + i * 8][tx] = s;
    }
    __syncthreads();
    #pragma unroll
    for (int i = 0; i < 4; ++i) {
        int n = n0 + ty + i * 8, k = k0 + tx;
        float v = tile[tx][ty + i * 8];
        size_t o = (size_t)n * 1024 + k;
        unsigned short h = f2bf_rne(v);
        H[o] = h;
        L[o] = f2bf_rne(v - bf2f(h));
    }
}

// -------------------- activation split + pad (rows) ------------------------
__global__ __launch_bounds__(256) void split_rows_kernel(
    const float* __restrict__ X, unsigned short* __restrict__ H, unsigned short* __restrict__ L,
    int C, int Cp)
{
    const int r = blockIdx.x;
    for (int c = threadIdx.x; c < Cp; c += 256) {
        float v = (c < C) ? X[(size_t)r * C + c] : 0.f;
        unsigned short h = f2bf_rne(v);
        size_t o = (size_t)r * Cp + c;
        H[o] = h;
        L[o] = f2bf_rne(v - bf2f(h));
    }
}

// ----------------- register-resident quantum circuit -----------------------
// amp idx = (lane<<4)|reg. Wire q stride S=1<<(9-q); S<16 reg bit, else lane bit.

template<int GATE, int Q>
__device__ __forceinline__ void apply_rot(float (&xr)[16], float (&xi)[16],
                                          const float (&tbl)[8], int lane)
{
    float are = lane_bcast(tbl[0], GATE), aim = lane_bcast(tbl[1], GATE);
    float bre = lane_bcast(tbl[2], GATE), bim = lane_bcast(tbl[3], GATE);
    float cre = lane_bcast(tbl[4], GATE), cim = lane_bcast(tbl[5], GATE);
    float dre = lane_bcast(tbl[6], GATE), dim_ = lane_bcast(tbl[7], GATE);
    constexpr int S = 1 << (9 - Q);
    if constexpr (S < 16) {
        #pragma unroll
        for (int p = 0; p < 8; ++p) {
            int r0 = (p / S) * (2 * S) + (p % S);
            int r1 = r0 + S;
            float x0r = xr[r0], x0i = xi[r0], x1r = xr[r1], x1i = xi[r1];
            xr[r0] = are * x0r - aim * x0i + bre * x1r - bim * x1i;
            xi[r0] = are * x0i + aim * x0r + bre * x1i + bim * x1r;
            xr[r1] = cre * x0r - cim * x0i + dre * x1r - dim_ * x1i;
            xi[r1] = cre * x0i + cim * x0r + dre * x1i + dim_ * x1r;
        }
    } else {
        constexpr int M = S >> 4;
        bool bit = (lane & M) != 0;
        float pre = bit ? dre : are, pim = bit ? dim_ : aim;
        float qre = bit ? cre : bre, qim = bit ? cim : bim;
        #pragma unroll
        for (int r = 0; r < 16; ++r) {
            float ore = lane_xor<M>(xr[r]);
            float oim = lane_xor<M>(xi[r]);
            float nr = pre * xr[r] - pim * xi[r] + qre * ore - qim * oim;
            float ni = pre * xi[r] + pim * xr[r] + qre * oim + qim * ore;
            xr[r] = nr; xi[r] = ni;
        }
    }
}

template<int C, int T>
__device__ __forceinline__ void apply_cnot(float (&xr)[16], float (&xi)[16], int lane)
{
    constexpr int SC = 1 << (9 - C), ST = 1 << (9 - T);
    if constexpr (SC < 16 && ST < 16) {
        #pragma unroll
        for (int r = 0; r < 16; ++r) {
            if ((r & SC) && !(r & ST)) {
                int j = r | ST;
                float t;
                t = xr[r]; xr[r] = xr[j]; xr[j] = t;
                t = xi[r]; xi[r] = xi[j]; xi[j] = t;
            }
        }
    } else if constexpr (SC < 16) {
        constexpr int MT = ST >> 4;
        #pragma unroll
        for (int r = 0; r < 16; ++r) {
            if (r & SC) {
                xr[r] = lane_xor<MT>(xr[r]);
                xi[r] = lane_xor<MT>(xi[r]);
            }
        }
    } else if constexpr (ST < 16) {
        constexpr int MC = SC >> 4;
        bool bit = (lane & MC) != 0;
        #pragma unroll
        for (int r = 0; r < 16; ++r) {
            if (!(r & ST)) {
                int j = r | ST;
                float a0 = xr[r], a1 = xr[j];
                xr[r] = bit ? a1 : a0;  xr[j] = bit ? a0 : a1;
                float b0 = xi[r], b1 = xi[j];
                xi[r] = bit ? b1 : b0;  xi[j] = bit ? b0 : b1;
            }
        }
    } else {
        constexpr int MC = SC >> 4, MT = ST >> 4;
        bool bit = (lane & MC) != 0;
        #pragma unroll
        for (int r = 0; r < 16; ++r) {
            float o = lane_xor<MT>(xr[r]);
            xr[r] = bit ? o : xr[r];
            float oi = lane_xor<MT>(xi[r]);
            xi[r] = bit ? oi : xi[r];
        }
    }
}

template<int L, int Q>
__device__ __forceinline__ void rots(float (&xr)[16], float (&xi)[16],
                                     const float (&tbl)[8], int lane) {
    apply_rot<L * 10 + Q, Q>(xr, xi, tbl, lane);
    if constexpr (Q < 9) rots<L, Q + 1>(xr, xi, tbl, lane);
}
template<int L, int Q>
__device__ __forceinline__ void cnots(float (&xr)[16], float (&xi)[16], int lane) {
    constexpr int R = (L % 9) + 1;
    apply_cnot<Q, (Q + R) % 10>(xr, xi, lane);
    if constexpr (Q < 9) cnots<L, Q + 1>(xr, xi, lane);
}

// X = X0 + X1 (split-K partials) -> circuit -> hi/lo bf16 split probs.
__global__ __launch_bounds__(256, 4) void circuit_reg_kernel(
    const float* __restrict__ X0, const float* __restrict__ X1,
    unsigned short* __restrict__ Ph, unsigned short* __restrict__ Pl,
    const float* __restrict__ G)
{
    const int lane = threadIdx.x & 63;
    const int item = blockIdx.x * 4 + (threadIdx.x >> 6);
    const size_t base = (size_t)item * 1024 + lane * 16;

    float tbl[8];
    {
        const float4* gp = (const float4*)(G + lane * 8);
        float4 t0 = gp[0], t1 = gp[1];
        tbl[0] = t0.x; tbl[1] = t0.y; tbl[2] = t0.z; tbl[3] = t0.w;
        tbl[4] = t1.x; tbl[5] = t1.y; tbl[6] = t1.z; tbl[7] = t1.w;
    }

    float xr[16], xi[16];
    const float4* xb0 = (const float4*)(X0 + base);
    const float4* xb1 = (const float4*)(X1 + base);
    #pragma unroll
    for (int v = 0; v < 4; ++v) {
        float4 f = xb0[v], g = xb1[v];
        xr[v * 4 + 0] = f.x + g.x; xr[v * 4 + 1] = f.y + g.y;
        xr[v * 4 + 2] = f.z + g.z; xr[v * 4 + 3] = f.w + g.w;
    }
    #pragma unroll
    for (int r = 0; r < 16; ++r) xi[r] = 0.f;

    float nrm = 0.f;
    #pragma unroll
    for (int r = 0; r < 16; ++r) nrm += xr[r] * xr[r];
    nrm += lane_xor<1>(nrm);
    nrm += lane_xor<2>(nrm);
    nrm += lane_xor<4>(nrm);
    nrm += lane_xor<8>(nrm);
    nrm += lane_xor<16>(nrm);
    nrm += lane_xor<32>(nrm);
    float inv = 1.0f / sqrtf(nrm);
    #pragma unroll
    for (int r = 0; r < 16; ++r) xr[r] *= inv;

    rots<0, 0>(xr, xi, tbl, lane);  cnots<0, 0>(xr, xi, lane);
    rots<1, 0>(xr, xi, tbl, lane);  cnots<1, 0>(xr, xi, lane);
    rots<2, 0>(xr, xi, tbl, lane);  cnots<2, 0>(xr, xi, lane);

    u16x8 h[2], lo[2];
    #pragma unroll
    for (int r = 0; r < 16; ++r) {
        float p = xr[r] * xr[r] + xi[r] * xi[r];
        unsigned short hh = f2bf_rne(p);
        h[r >> 3][r & 7] = hh;
        lo[r >> 3][r & 7] = f2bf_rne(p - bf2f(hh));
    }
    *(u16x8*)(Ph + base) = h[0];
    *(u16x8*)(Ph + base + 8) = h[1];
    *(u16x8*)(Pl + base) = lo[0];
    *(u16x8*)(Pl + base + 8) = lo[1];
}

// ------------------------- abs + row-normalize -----------------------------
__global__ __launch_bounds__(256) void absnorm_kernel(
    const float* __restrict__ X0, const float* __restrict__ X1,
    float* __restrict__ out, int N, int stride)
{
    __shared__ float red[4];
    const int row = blockIdx.x;
    const int tid = threadIdx.x;
    const float* x0 = X0 + (size_t)row * stride;
    const float* x1 = X1 + (size_t)row * stride;

    float s = 0.f;
    for (int i = tid; i < N; i += 256) s += fabsf(x0[i] + x1[i]);
    #pragma unroll
    for (int off = 32; off > 0; off >>= 1) s += __shfl_down(s, off);
    if ((tid & 63) == 0) red[tid >> 6] = s;
    __syncthreads();
    float inv = 1.0f / (red[0] + red[1] + red[2] + red[3]);
    for (int i = tid; i < N; i += 256)
        out[(size_t)row * N + i] = fabsf(x0[i] + x1[i]) * inv;
}

// ---------------------------------------------------------------------------
extern "C" void kernel_launch(void* const* d_in, const int* in_sizes, int n_in,
                              void* d_out, int out_size, void* d_ws, size_t ws_size,
                              hipStream_t stream)
{
    const float* inputs = (const float*)d_in[0];
    const float* wEnc   = (const float*)d_in[1];
    const float* wDec   = (const float*)d_in[2];
    const float* W0     = (const float*)d_in[3];
    const float* b0     = (const float*)d_in[4];
    const float* W1     = (const float*)d_in[5];
    const float* b1     = (const float*)d_in[6];
    const float* W2     = (const float*)d_in[7];
    const float* b2     = (const float*)d_in[8];
    const float* W3     = (const float*)d_in[9];
    const float* b3     = (const float*)d_in[10];
    float* out = (float*)d_out;

    char* w = (char*)d_ws;
    auto alloc = [&](size_t bytes) { char* p = w; w += (bytes + 255) & ~(size_t)255; return p; };

    unsigned short* Bt0h  = (unsigned short*)alloc((size_t)1024 * 1024 * 2);
    unsigned short* Bt0l  = (unsigned short*)alloc((size_t)1024 * 1024 * 2);
    unsigned short* Bt2h  = (unsigned short*)alloc((size_t)1024 * 2048 * 2);
    unsigned short* Bt2l  = (unsigned short*)alloc((size_t)1024 * 2048 * 2);
    unsigned short* Bt3h  = (unsigned short*)alloc((size_t)1024 * 1024 * 2);
    unsigned short* Bt3l  = (unsigned short*)alloc((size_t)1024 * 1024 * 2);
    unsigned short* Bt12h = (unsigned short*)alloc((size_t)1024 * 1024 * 2);
    unsigned short* Bt12l = (unsigned short*)alloc((size_t)1024 * 1024 * 2);
    unsigned short* W1h   = (unsigned short*)alloc((size_t)1024 * 2048 * 2);
    unsigned short* W1l   = (unsigned short*)alloc((size_t)1024 * 2048 * 2);
    float*          b3p   = (float*)alloc(1024 * 4);
    float*          b12   = (float*)alloc(1024 * 4);
    float*          G     = (float*)alloc(2 * 512 * 4);   // enc @ G, dec @ G+512
    unsigned short* Ah    = (unsigned short*)alloc((size_t)B_SZ * 1024 * 2);
    unsigned short* Al    = (unsigned short*)alloc((size_t)B_SZ * 1024 * 2);
    unsigned short* ph    = (unsigned short*)alloc((size_t)B_SZ * 1024 * 2);
    unsigned short* pl    = (unsigned short*)alloc((size_t)B_SZ * 1024 * 2);
    float*          P     = (float*)alloc((size_t)2 * B_SZ * 1024 * 4);  // split-K partials
    float* P12 = P;                 // 8 x [1024x1024] fp32 (32 MB) aliased; dead before G0
    const size_t ZS = (size_t)B_SZ * 1024;

    dim3 blk256(256);

    // ---- per-call prep (2 merged launches) ----
    prep_weights_kernel<<<5120, blk256, 0, stream>>>(
        W0, Bt0h, Bt0l, W2, Bt2h, Bt2l, W3, Bt3h, Bt3l, W1, W1h, W1l);
    prep_misc_kernel<<<21, blk256, 0, stream>>>(b1, W2, b2, b12, b3, b3p, wEnc, wDec, G);
    split_rows_kernel<<<B_SZ, blk256, 0, stream>>>(inputs, Ah, Al, 1000, 1024);

    // ---- W12 = W1 @ W2 (split-K=8) -> transpose+split -> Bt12 ----
    gemm3_mfma<<<dim3(8, 8, 8), 512, 0, stream>>>(
        W1h, W1l, Bt2h, Bt2l, nullptr, P12, 2048, 1024, 256, (size_t)1 << 20);
    tsplit8_kernel<<<dim3(32, 32), blk256, 0, stream>>>(P12, Bt12h, Bt12l);

    // ---- pipeline ----
    gemm3_mfma<<<dim3(8, 32, 2), 512, 0, stream>>>(
        Ah, Al, Bt0h, Bt0l, b0, P, 1024, 1024, 512, ZS);
    circuit_reg_kernel<<<B_SZ / 4, blk256, 0, stream>>>(P, P + ZS, ph, pl, G);
    gemm3_mfma<<<dim3(8, 32, 2), 512, 0, stream>>>(
        ph, pl, Bt12h, Bt12l, b12, P, 1024, 1024, 512, ZS);
    circuit_reg_kernel<<<B_SZ / 4, blk256, 0, stream>>>(P, P + ZS, ph, pl, G + 512);
    gemm3_mfma<<<dim3(8, 32, 2), 512, 0, stream>>>(
        ph, pl, Bt3h, Bt3l, b3p, P, 1024, 1024, 512, ZS);
    absnorm_kernel<<<B_SZ, blk256, 0, stream>>>(P, P + ZS, out, 1000, 1024);
}